// Round 1
// baseline (1286.994 us; speedup 1.0000x reference)
//
#include <hip/hip_runtime.h>
#include <math.h>

#define B_ 4
#define F_ 256
#define H_ 64
#define W_ 64
#define C_ 19
#define S_ 256
#define N_ (B_*H_*W_)      // 16384 pixels
#define M_ (C_*2*S_)       // 9728 memory rows
#define BK 32

// ---------------- kernel 1a: per-pixel inverse feature norms ----------------
__global__ __launch_bounds__(256) void k_feat_norms(const float* __restrict__ pred,
                                                    float* __restrict__ inv_fn) {
    int n = blockIdx.x * 256 + threadIdx.x;   // grid = 64 blocks
    int b  = n >> 12;                         // / (H*W)
    int hw = n & 4095;
    const float* p = pred + (((size_t)b * F_) << 12) + hw;
    float s = 0.f;
    #pragma unroll 8
    for (int f = 0; f < F_; ++f) {
        float v = p[(size_t)f << 12];
        s += v * v;
    }
    inv_fn[n] = 1.0f / sqrtf(s);
}

// ---------------- kernel 1b: per-memory-row inverse norms (wave per row) ----
__global__ __launch_bounds__(256) void k_mem_norms(const float* __restrict__ mem,
                                                   float* __restrict__ inv_mn) {
    int row  = blockIdx.x * 4 + (threadIdx.x >> 6);
    int lane = threadIdx.x & 63;
    const float4* p = (const float4*)(mem + (size_t)row * F_);
    float4 a = p[lane];                       // 64 lanes x 4 = 256 elements
    float s = a.x*a.x + a.y*a.y + a.z*a.z + a.w*a.w;
    #pragma unroll
    for (int off = 32; off; off >>= 1) s += __shfl_xor(s, off, 64);
    if (lane == 0) inv_mn[row] = 1.0f / sqrtf(s);
}

// ---------------- kernel 2: tiled cos->exp GEMM ----------------
// grid = (M_/64, N_/64), block = 256 (16x16 threads, 4x4 micro-tile)
__global__ __launch_bounds__(256) void k_gemm(const float* __restrict__ pred,
                                              const float* __restrict__ mem,
                                              const int*   __restrict__ labels,
                                              const float* __restrict__ inv_fn,
                                              const float* __restrict__ inv_mn,
                                              float* __restrict__ total,
                                              float* __restrict__ classbuf) {
    __shared__ float As[BK * 64];     // [k][n], stride 64 (write stride-1, read broadcast)
    __shared__ float Bs[BK * 68];     // [k][m], stride 68 (pad keeps read conflicts ~2-way)
    __shared__ float invf_s[64], invm_s[64];
    __shared__ int   lab_s[64];

    int t  = threadIdx.x;
    int m0 = blockIdx.x * 64;
    int n0 = blockIdx.y * 64;
    int b   = n0 >> 12;               // whole 64-row tile shares one batch image
    int hw0 = n0 & 4095;

    if (t < 64) {
        invf_s[t] = inv_fn[n0 + t];
        invm_s[t] = inv_mn[m0 + t];
        lab_s[t]  = labels[n0 + t];
    }

    int tx = t & 15, ty = t >> 4;
    float acc[4][4] = {};

    const float* Abase = pred + ((size_t)b * F_ << 12) + hw0;
    const float* Bbase = mem + (size_t)m0 * F_;

    for (int k0 = 0; k0 < F_; k0 += BK) {
        __syncthreads();
        // A tile: 32k x 64n. thread: i = t&63 (coalesced), k = (t>>6)*8 + q
        {
            int i  = t & 63;
            int kk = (t >> 6) * 8;
            #pragma unroll
            for (int q = 0; q < 8; ++q)
                As[(kk + q) * 64 + i] = Abase[((size_t)(k0 + kk + q)) << 12 | 0] + 0.f,  // placeholder avoided below
                As[(kk + q) * 64 + i] = Abase[((size_t)(k0 + kk + q)) * 4096 + i];
            // B tile: 64m x 32k, staged transposed -> Bs[k][m]
            int f  = t & 31;
            int mm = t >> 5;
            #pragma unroll
            for (int q = 0; q < 8; ++q)
                Bs[f * 68 + mm + q * 8] = Bbase[(size_t)(mm + q * 8) * F_ + k0 + f];
        }
        __syncthreads();
        #pragma unroll
        for (int k = 0; k < BK; ++k) {
            float4 a  = *(const float4*)&As[k * 64 + ty * 4];
            float4 bv = *(const float4*)&Bs[k * 68 + tx * 4];
            acc[0][0] += a.x * bv.x; acc[0][1] += a.x * bv.y; acc[0][2] += a.x * bv.z; acc[0][3] += a.x * bv.w;
            acc[1][0] += a.y * bv.x; acc[1][1] += a.y * bv.y; acc[1][2] += a.y * bv.z; acc[1][3] += a.y * bv.w;
            acc[2][0] += a.z * bv.x; acc[2][1] += a.z * bv.y; acc[2][2] += a.z * bv.z; acc[2][3] += a.z * bv.w;
            acc[3][0] += a.w * bv.x; acc[3][1] += a.w * bv.y; acc[3][2] += a.w * bv.z; acc[3][3] += a.w * bv.w;
        }
    }

    // epilogue: cos -> E = exp(2*cos)
    float E[4][4];
    #pragma unroll
    for (int i = 0; i < 4; ++i) {
        float invf = invf_s[ty * 4 + i];
        #pragma unroll
        for (int j = 0; j < 4; ++j) {
            float cosv = acc[i][j] * invf * invm_s[tx * 4 + j];
            E[i][j] = __expf(2.0f * cosv);
        }
    }
    // row sums across the 16 tx lanes -> atomics into total[n]
    #pragma unroll
    for (int i = 0; i < 4; ++i) {
        float rs = E[i][0] + E[i][1] + E[i][2] + E[i][3];
        rs += __shfl_xor(rs, 1, 64);
        rs += __shfl_xor(rs, 2, 64);
        rs += __shfl_xor(rs, 4, 64);
        rs += __shfl_xor(rs, 8, 64);
        if (tx == 0) atomicAdd(&total[n0 + ty * 4 + i], rs);
    }
    // scatter E into the pixel's own class block (tile is fully inside one class: 512 % 64 == 0)
    int cblk = m0 >> 9;
    int moff = m0 & 511;
    #pragma unroll
    for (int i = 0; i < 4; ++i) {
        if (lab_s[ty * 4 + i] == cblk) {
            int n = n0 + ty * 4 + i;
            float4 w = make_float4(E[i][0], E[i][1], E[i][2], E[i][3]);
            *(float4*)&classbuf[(size_t)n * 512 + moff + tx * 4] = w;
        }
    }
}

// ---------------- kernel 3: per-pixel log terms (wave per pixel) ----------------
__global__ __launch_bounds__(256) void k_terms(const float* __restrict__ classbuf,
                                               const float* __restrict__ total,
                                               const int*   __restrict__ labels,
                                               const int*   __restrict__ mask,
                                               const int*   __restrict__ wmem,
                                               float* __restrict__ class_sum,
                                               int*   __restrict__ class_cnt) {
    int wid  = threadIdx.x >> 6;
    int lane = threadIdx.x & 63;
    int n = blockIdx.x * 4 + wid;
    if (!mask[n]) return;                       // wave-uniform branch
    int lab = labels[n];
    int wm  = wmem[n];
    const float4* p = (const float4*)&classbuf[(size_t)n * 512];
    float4 v0 = p[lane * 2];
    float4 v1 = p[lane * 2 + 1];
    float s = v0.x + v0.y + v0.z + v0.w + v1.x + v1.y + v1.z + v1.w;
    #pragma unroll
    for (int off = 1; off < 64; off <<= 1) s += __shfl_xor(s, off, 64);
    float down = total[n] - s;                  // total minus this class's block sum
    int lo = (wm == 1) ? 0 : 32;                // wm==1 -> first half [0,S), wm==0 -> second half
    float ts = 0.f;
    if (lane >= lo && lane < lo + 32) {
        float vv[8] = {v0.x, v0.y, v0.z, v0.w, v1.x, v1.y, v1.z, v1.w};
        #pragma unroll
        for (int q = 0; q < 8; ++q) {
            float pv = vv[q];
            ts += -logf(pv / (pv + down + 1e-12f) + 1e-12f);
        }
    }
    #pragma unroll
    for (int off = 1; off < 64; off <<= 1) ts += __shfl_xor(ts, off, 64);
    if (lane == 0) {
        atomicAdd(&class_sum[lab], ts);
        atomicAdd(&class_cnt[lab], 1);
    }
}

// ---------------- kernel 4: final class average ----------------
__global__ void k_final(const float* __restrict__ class_sum,
                        const int*   __restrict__ class_cnt,
                        float* __restrict__ out) {
    if (threadIdx.x == 0 && blockIdx.x == 0) {
        float loss = 0.f, kc = 0.f;
        for (int c = 0; c < C_; ++c) {
            int cnt = class_cnt[c];
            if (cnt > 0) {
                loss += class_sum[c] / ((float)cnt * (float)S_);
                kc += 1.f;
            }
        }
        out[0] = loss / fmaxf(kc, 1.f);
    }
}

extern "C" void kernel_launch(void* const* d_in, const int* in_sizes, int n_in,
                              void* d_out, int out_size, void* d_ws, size_t ws_size,
                              hipStream_t stream) {
    const float* mem    = (const float*)d_in[0];
    const float* pred   = (const float*)d_in[1];
    const int*   labels = (const int*)  d_in[2];
    const int*   mask   = (const int*)  d_in[3];
    const int*   wmem   = (const int*)  d_in[4];
    float* out = (float*)d_out;

    float* ws        = (float*)d_ws;
    float* inv_fn    = ws;                       // N_ floats
    float* inv_mn    = ws + N_;                  // M_ floats
    float* total     = ws + N_ + M_;             // N_ floats  (zero-init)
    float* class_sum = total + N_;               // C_ floats  (zero-init)
    int*   class_cnt = (int*)(class_sum + C_);   // C_ ints    (zero-init)
    // align classbuf to 16B: offset in floats = N_+M_+N_+2*C_ = 42534 -> pad to 42536
    float* classbuf  = ws + 42536;               // N_*512 floats = 33.5 MB

    // zero total + class_sum + class_cnt (contiguous region)
    hipMemsetAsync(total, 0, (size_t)(N_ + 2 * C_) * sizeof(float), stream);

    k_feat_norms<<<N_ / 256, 256, 0, stream>>>(pred, inv_fn);
    k_mem_norms<<<M_ / 4, 256, 0, stream>>>(mem, inv_mn);

    dim3 g2(M_ / 64, N_ / 64);
    k_gemm<<<g2, 256, 0, stream>>>(pred, mem, labels, inv_fn, inv_mn, total, classbuf);

    k_terms<<<N_ / 4, 256, 0, stream>>>(classbuf, total, labels, mask, wmem,
                                        class_sum, class_cnt);
    k_final<<<1, 64, 0, stream>>>(class_sum, class_cnt, out);
}

// Round 2
// 401.666 us; speedup vs baseline: 3.2041x; 3.2041x over previous
//
#include <hip/hip_runtime.h>
#include <hip/hip_bf16.h>
#include <math.h>

#define B_ 4
#define F_ 256
#define H_ 64
#define W_ 64
#define C_ 19
#define S_ 256
#define N_ (B_*H_*W_)      // 16384 pixels
#define M_ (C_*2*S_)       // 9728 memory rows

typedef __bf16 bf16_t;
typedef bf16_t bf16x8 __attribute__((ext_vector_type(8)));
typedef float floatx4 __attribute__((ext_vector_type(4)));

#define AS1 __attribute__((address_space(1)))
#define AS3 __attribute__((address_space(3)))

// ---------------- kernel 1a: per-pixel inverse feature norms ----------------
__global__ __launch_bounds__(256) void k_feat_norms(const float* __restrict__ pred,
                                                    float* __restrict__ inv_fn) {
    int n = blockIdx.x * 256 + threadIdx.x;   // grid = 64 blocks
    int b  = n >> 12;
    int hw = n & 4095;
    const float* p = pred + (((size_t)b * F_) << 12) + hw;
    float s = 0.f;
    #pragma unroll 8
    for (int f = 0; f < F_; ++f) {
        float v = p[(size_t)f << 12];
        s += v * v;
    }
    inv_fn[n] = 1.0f / sqrtf(s);
}

// ---------------- kernel 1b: per-memory-row inverse norms (wave per row) ----
__global__ __launch_bounds__(256) void k_mem_norms(const float* __restrict__ mem,
                                                   float* __restrict__ inv_mn) {
    int row  = blockIdx.x * 4 + (threadIdx.x >> 6);
    int lane = threadIdx.x & 63;
    const float4* p = (const float4*)(mem + (size_t)row * F_);
    float4 a = p[lane];
    float s = a.x*a.x + a.y*a.y + a.z*a.z + a.w*a.w;
    #pragma unroll
    for (int off = 32; off; off >>= 1) s += __shfl_xor(s, off, 64);
    if (lane == 0) inv_mn[row] = 1.0f / sqrtf(s);
}

// ---------------- kernel 2a: normalize + transpose pred -> A16[n][f] bf16 ----
// grid = 4(b) * 4(ftile) * 64(hwtile) = 1024 blocks
__global__ __launch_bounds__(256) void k_convA(const float* __restrict__ pred,
                                               const float* __restrict__ inv_fn,
                                               __hip_bfloat16* __restrict__ A16) {
    __shared__ float T[64][65];
    int bid = blockIdx.x;
    int hwt = bid & 63;
    int ft  = (bid >> 6) & 3;
    int b   = bid >> 8;
    int hw0 = hwt * 64, f0 = ft * 64;
    int t = threadIdx.x;
    int col   = t & 63;       // hw_local
    int rbase = t >> 6;       // 0..3
    const float* base = pred + ((size_t)b * F_ + f0) * 4096 + hw0;
    float invf = inv_fn[b * 4096 + hw0 + col];
    #pragma unroll
    for (int q = 0; q < 16; ++q) {
        int row = q * 4 + rbase;           // f_local
        T[row][col] = base[(size_t)row * 4096 + col] * invf;
    }
    __syncthreads();
    int j  = t >> 2;                        // hw_local (output row)
    int fc = (t & 3) * 16;                  // f chunk
    __hip_bfloat16 tmp[16];
    #pragma unroll
    for (int s = 0; s < 16; ++s) tmp[s] = __float2bfloat16(T[fc + s][j]);
    float4* dst = (float4*)&A16[((size_t)(b * 4096 + hw0 + j)) * F_ + f0 + fc];
    float4* src = (float4*)tmp;
    dst[0] = src[0];
    dst[1] = src[1];
}

// ---------------- kernel 2b: normalize mem -> B16[m][f] bf16 ----
// grid = M_*32/256 = 1216 blocks; each thread does 8 elements
__global__ __launch_bounds__(256) void k_convB(const float* __restrict__ mem,
                                               const float* __restrict__ inv_mn,
                                               __hip_bfloat16* __restrict__ B16) {
    int idx = blockIdx.x * 256 + threadIdx.x;
    int row = idx >> 5;
    int off = (idx & 31) * 8;
    float invm = inv_mn[row];
    const float4* src = (const float4*)(mem + (size_t)row * F_ + off);
    float4 v0 = src[0], v1 = src[1];
    __hip_bfloat16 tmp[8];
    tmp[0] = __float2bfloat16(v0.x * invm);
    tmp[1] = __float2bfloat16(v0.y * invm);
    tmp[2] = __float2bfloat16(v0.z * invm);
    tmp[3] = __float2bfloat16(v0.w * invm);
    tmp[4] = __float2bfloat16(v1.x * invm);
    tmp[5] = __float2bfloat16(v1.y * invm);
    tmp[6] = __float2bfloat16(v1.z * invm);
    tmp[7] = __float2bfloat16(v1.w * invm);
    *(float4*)&B16[(size_t)row * F_ + off] = *(float4*)tmp;
}

// ---------------- kernel 3: MFMA cos->exp GEMM (m97 structure) ----------------
// grid = (M_/128=76, N_/128=128), block = 256 (4 waves), each wave a 64x64 quadrant
__global__ __launch_bounds__(256) void k_mfma(const __hip_bfloat16* __restrict__ A16,
                                              const __hip_bfloat16* __restrict__ B16,
                                              const int* __restrict__ labels,
                                              float* __restrict__ total,
                                              float* __restrict__ classbuf) {
    __shared__ __hip_bfloat16 As[128 * 32];   // [n][k], k-contiguous, unpadded (global_load_lds layout)
    __shared__ __hip_bfloat16 Bs[128 * 32];   // [m][k]
    __shared__ int lab_s[128];

    int t = threadIdx.x;
    int w = t >> 6, lane = t & 63;
    int m0 = blockIdx.x * 128;
    int n0 = blockIdx.y * 128;
    if (t < 128) lab_s[t] = labels[n0 + t];

    int nq = (w & 1) * 64, mq = (w >> 1) * 64;
    floatx4 acc[4][4];
    #pragma unroll
    for (int i = 0; i < 4; ++i)
        #pragma unroll
        for (int j = 0; j < 4; ++j) acc[i][j] = (floatx4){0.f, 0.f, 0.f, 0.f};

    // staging: wave w loads rows [w*32, w*32+32) of both tiles, 16B/lane
    int srow = w * 32 + (lane >> 2);
    int scol = (lane & 3) * 8;
    const __hip_bfloat16* gA0 = A16 + (size_t)(n0 + srow) * F_ + scol;
    const __hip_bfloat16* gA1 = gA0 + 16 * F_;
    const __hip_bfloat16* gB0 = B16 + (size_t)(m0 + srow) * F_ + scol;
    const __hip_bfloat16* gB1 = gB0 + 16 * F_;
    __hip_bfloat16* lA0 = &As[(w * 32) * 32];
    __hip_bfloat16* lA1 = &As[(w * 32 + 16) * 32];
    __hip_bfloat16* lB0 = &Bs[(w * 32) * 32];
    __hip_bfloat16* lB1 = &Bs[(w * 32 + 16) * 32];

    int fk  = (lane >> 4) * 8;                   // k offset of this lane's fragment
    int frA = (nq + (lane & 15)) * 32 + fk;
    int frB = (mq + (lane & 15)) * 32 + fk;

    for (int k0 = 0; k0 < F_; k0 += 32) {
        __syncthreads();
        __builtin_amdgcn_global_load_lds((const AS1 unsigned int*)(gA0 + k0), (AS3 unsigned int*)lA0, 16, 0, 0);
        __builtin_amdgcn_global_load_lds((const AS1 unsigned int*)(gA1 + k0), (AS3 unsigned int*)lA1, 16, 0, 0);
        __builtin_amdgcn_global_load_lds((const AS1 unsigned int*)(gB0 + k0), (AS3 unsigned int*)lB0, 16, 0, 0);
        __builtin_amdgcn_global_load_lds((const AS1 unsigned int*)(gB1 + k0), (AS3 unsigned int*)lB1, 16, 0, 0);
        __syncthreads();
        bf16x8 af[4], bfr[4];
        #pragma unroll
        for (int ni = 0; ni < 4; ++ni) af[ni]  = *(const bf16x8*)&As[frA + ni * 16 * 32];
        #pragma unroll
        for (int mi = 0; mi < 4; ++mi) bfr[mi] = *(const bf16x8*)&Bs[frB + mi * 16 * 32];
        #pragma unroll
        for (int ni = 0; ni < 4; ++ni)
            #pragma unroll
            for (int mi = 0; mi < 4; ++mi)
                acc[ni][mi] = __builtin_amdgcn_mfma_f32_16x16x32_bf16(af[ni], bfr[mi], acc[ni][mi], 0, 0, 0);
    }

    // epilogue: E = exp(2*cos); row sums -> total; own-class scatter -> classbuf
    int cls   = m0 >> 9;                 // tile lies in one class (512 % 128 == 0)
    int mbase = (m0 & 511) + mq;         // within-class column base for this wave
    int colL  = lane & 15;               // C/D: col = lane&15
    int rgrp  = (lane >> 4) * 4;         // C/D: row = (lane>>4)*4 + reg
    #pragma unroll
    for (int ni = 0; ni < 4; ++ni) {
        float Ev[4][4];
        float rsum[4] = {0.f, 0.f, 0.f, 0.f};
        #pragma unroll
        for (int mi = 0; mi < 4; ++mi)
            #pragma unroll
            for (int r = 0; r < 4; ++r) {
                float e = __expf(2.0f * acc[ni][mi][r]);
                Ev[mi][r] = e;
                rsum[r] += e;
            }
        #pragma unroll
        for (int r = 0; r < 4; ++r) {
            float s = rsum[r];
            s += __shfl_xor(s, 1, 64);
            s += __shfl_xor(s, 2, 64);
            s += __shfl_xor(s, 4, 64);
            s += __shfl_xor(s, 8, 64);
            int nrow = nq + ni * 16 + rgrp + r;
            if (colL == 0) atomicAdd(&total[n0 + nrow], s);
            if (lab_s[nrow] == cls) {
                size_t base = (size_t)(n0 + nrow) * 512 + mbase;
                #pragma unroll
                for (int mi = 0; mi < 4; ++mi)
                    classbuf[base + mi * 16 + colL] = Ev[mi][r];
            }
        }
    }
}

// ---------------- kernel 4: per-pixel log terms (wave per pixel) ----------------
__global__ __launch_bounds__(256) void k_terms(const float* __restrict__ classbuf,
                                               const float* __restrict__ total,
                                               const int*   __restrict__ labels,
                                               const int*   __restrict__ mask,
                                               const int*   __restrict__ wmem,
                                               float* __restrict__ class_sum,
                                               int*   __restrict__ class_cnt) {
    int wid  = threadIdx.x >> 6;
    int lane = threadIdx.x & 63;
    int n = blockIdx.x * 4 + wid;
    if (!mask[n]) return;                       // wave-uniform branch
    int lab = labels[n];
    int wm  = wmem[n];
    const float4* p = (const float4*)&classbuf[(size_t)n * 512];
    float4 v0 = p[lane * 2];
    float4 v1 = p[lane * 2 + 1];
    float s = v0.x + v0.y + v0.z + v0.w + v1.x + v1.y + v1.z + v1.w;
    #pragma unroll
    for (int off = 1; off < 64; off <<= 1) s += __shfl_xor(s, off, 64);
    float down = total[n] - s;
    int lo = (wm == 1) ? 0 : 32;                // wm==1 -> first half [0,S)
    float ts = 0.f;
    if (lane >= lo && lane < lo + 32) {
        float vv[8] = {v0.x, v0.y, v0.z, v0.w, v1.x, v1.y, v1.z, v1.w};
        #pragma unroll
        for (int q = 0; q < 8; ++q) {
            float pv = vv[q];
            ts += -logf(pv / (pv + down + 1e-12f) + 1e-12f);
        }
    }
    #pragma unroll
    for (int off = 1; off < 64; off <<= 1) ts += __shfl_xor(ts, off, 64);
    if (lane == 0) {
        atomicAdd(&class_sum[lab], ts);
        atomicAdd(&class_cnt[lab], 1);
    }
}

// ---------------- kernel 5: final class average ----------------
__global__ void k_final(const float* __restrict__ class_sum,
                        const int*   __restrict__ class_cnt,
                        float* __restrict__ out) {
    if (threadIdx.x == 0 && blockIdx.x == 0) {
        float loss = 0.f, kc = 0.f;
        for (int c = 0; c < C_; ++c) {
            int cnt = class_cnt[c];
            if (cnt > 0) {
                loss += class_sum[c] / ((float)cnt * (float)S_);
                kc += 1.f;
            }
        }
        out[0] = loss / fmaxf(kc, 1.f);
    }
}

extern "C" void kernel_launch(void* const* d_in, const int* in_sizes, int n_in,
                              void* d_out, int out_size, void* d_ws, size_t ws_size,
                              hipStream_t stream) {
    const float* mem    = (const float*)d_in[0];
    const float* pred   = (const float*)d_in[1];
    const int*   labels = (const int*)  d_in[2];
    const int*   mask   = (const int*)  d_in[3];
    const int*   wmem   = (const int*)  d_in[4];
    float* out = (float*)d_out;

    float* ws        = (float*)d_ws;
    float* inv_fn    = ws;                       // N_ floats
    float* inv_mn    = ws + N_;                  // M_ floats
    float* total     = ws + N_ + M_;             // N_ floats  (zero-init)
    float* class_sum = total + N_;               // C_ floats  (zero-init)
    int*   class_cnt = (int*)(class_sum + C_);   // C_ ints    (zero-init)
    float* classbuf  = ws + 42536;               // N_*512 floats = 33.5 MB (16B aligned)
    __hip_bfloat16* A16 = (__hip_bfloat16*)(ws + 42536 + (size_t)N_ * 512);          // 8 MB
    __hip_bfloat16* B16 = (__hip_bfloat16*)(ws + 42536 + (size_t)N_ * 512 + 2097152); // 4.75 MB

    hipMemsetAsync(total, 0, (size_t)(N_ + 2 * C_) * sizeof(float), stream);

    k_feat_norms<<<N_ / 256, 256, 0, stream>>>(pred, inv_fn);
    k_mem_norms<<<M_ / 4, 256, 0, stream>>>(mem, inv_mn);
    k_convA<<<1024, 256, 0, stream>>>(pred, inv_fn, A16);
    k_convB<<<M_ * 32 / 256, 256, 0, stream>>>(mem, inv_mn, B16);

    dim3 g3(M_ / 128, N_ / 128);
    k_mfma<<<g3, 256, 0, stream>>>(A16, B16, labels, total, classbuf);

    k_terms<<<N_ / 4, 256, 0, stream>>>(classbuf, total, labels, mask, wmem,
                                        class_sum, class_cnt);
    k_final<<<1, 64, 0, stream>>>(class_sum, class_cnt, out);
}

// Round 3
// 400.012 us; speedup vs baseline: 3.2174x; 1.0041x over previous
//
#include <hip/hip_runtime.h>
#include <hip/hip_bf16.h>
#include <math.h>

#define B_ 4
#define F_ 256
#define H_ 64
#define W_ 64
#define C_ 19
#define S_ 256
#define N_ (B_*H_*W_)      // 16384 pixels
#define M_ (C_*2*S_)       // 9728 memory rows

typedef __bf16 bf16_t;
typedef bf16_t bf16x8 __attribute__((ext_vector_type(8)));
typedef float floatx4 __attribute__((ext_vector_type(4)));

#define AS1 __attribute__((address_space(1)))
#define AS3 __attribute__((address_space(3)))

#define ZERO_FLOATS (N_ + 2*C_)   // total + class_sum + class_cnt = 16422

// ---------------- kernel 1: fused prep ----------------
// blocks [0,256): normalize+transpose pred -> A16[n][f] (includes feat norms)
// blocks [256, 256+M_/4): normalize mem -> B16[m][f] (includes mem norms)
// blocks [256+M_/4, +17): zero total/class_sum/class_cnt
__global__ __launch_bounds__(256) void k_prep(const float* __restrict__ pred,
                                              const float* __restrict__ mem,
                                              __hip_bfloat16* __restrict__ A16,
                                              __hip_bfloat16* __restrict__ B16,
                                              float* __restrict__ zero_base) {
    int bid = blockIdx.x;
    int t = threadIdx.x;
    if (bid < 256) {
        // ---- conv A: block = (b, hw-tile of 64); thread (q = t>>6, j = t&63)
        __shared__ float part[4][64];
        __shared__ float invf_s[64];
        int b = bid >> 6, hw0 = (bid & 63) * 64;
        int j = t & 63, q = t >> 6;
        const float* base = pred + ((size_t)b * F_ + q * 64) * 4096 + hw0 + j;
        float v[64];
        float s = 0.f;
        #pragma unroll
        for (int i = 0; i < 64; ++i) {
            float x = base[(size_t)i * 4096];
            v[i] = x;
            s += x * x;
        }
        part[q][j] = s;
        __syncthreads();
        if (t < 64) invf_s[t] = 1.0f / sqrtf(part[0][t] + part[1][t] + part[2][t] + part[3][t]);
        __syncthreads();
        float invf = invf_s[j];
        __hip_bfloat16* dst = A16 + (size_t)(b * 4096 + hw0 + j) * F_ + q * 64;
        #pragma unroll
        for (int c = 0; c < 8; ++c) {
            __hip_bfloat16 tmp[8];
            #pragma unroll
            for (int u = 0; u < 8; ++u) tmp[u] = __float2bfloat16(v[c * 8 + u] * invf);
            *(float4*)&dst[c * 8] = *(float4*)tmp;
        }
    } else if (bid < 256 + M_ / 4) {
        // ---- conv B: wave per memory row
        int row  = (bid - 256) * 4 + (t >> 6);
        int lane = t & 63;
        float4 a = ((const float4*)(mem + (size_t)row * F_))[lane];
        float s = a.x*a.x + a.y*a.y + a.z*a.z + a.w*a.w;
        #pragma unroll
        for (int off = 32; off; off >>= 1) s += __shfl_xor(s, off, 64);
        float invm = 1.0f / sqrtf(s);
        __hip_bfloat16 tmp[4];
        tmp[0] = __float2bfloat16(a.x * invm);
        tmp[1] = __float2bfloat16(a.y * invm);
        tmp[2] = __float2bfloat16(a.z * invm);
        tmp[3] = __float2bfloat16(a.w * invm);
        *(float2*)&B16[(size_t)row * F_ + lane * 4] = *(float2*)tmp;
    } else {
        // ---- zero accumulators
        int idx = (bid - (256 + M_ / 4)) * 1024 + t * 4;
        #pragma unroll
        for (int u = 0; u < 4; ++u)
            if (idx + u < ZERO_FLOATS) zero_base[idx + u] = 0.f;
    }
}

// ---------------- kernel 2: MFMA cos->exp GEMM ----------------
// grid = (M_/128=76, N_/128=128), block = 256 (4 waves), each wave a 64x64 quadrant.
// BK=64. LDS layout: 16 sub-blocks of 1 KB per operand; sub-block sb = g*2+s
// (g = 16-row group, s = 32-k half). Within a sub-block the byte order is
// lane*16 with lane = (kchunk<<4)|row  -> fragment ds_read_b128 at base+lane*16
// is contiguous (zero bank conflicts), and global_load_lds staging writes the
// same order by construction.
__global__ __launch_bounds__(256) void k_mfma(const __hip_bfloat16* __restrict__ A16,
                                              const __hip_bfloat16* __restrict__ B16,
                                              const int* __restrict__ labels,
                                              float* __restrict__ total,
                                              float* __restrict__ classbuf) {
    __shared__ __hip_bfloat16 As[128 * 64];   // 16 KB
    __shared__ __hip_bfloat16 Bs[128 * 64];   // 16 KB
    __shared__ int lab_s[128];

    int t = threadIdx.x;
    int w = t >> 6, lane = t & 63;
    int m0 = blockIdx.x * 128;
    int n0 = blockIdx.y * 128;
    if (t < 128) lab_s[t] = labels[n0 + t];

    int nq = (w & 1) * 64, mq = (w >> 1) * 64;
    floatx4 acc[4][4];
    #pragma unroll
    for (int i = 0; i < 4; ++i)
        #pragma unroll
        for (int j = 0; j < 4; ++j) acc[i][j] = (floatx4){0.f, 0.f, 0.f, 0.f};

    int rowl = lane & 15;          // row within 16-row group
    int kch  = lane >> 4;          // 8-element k chunk 0..3

    for (int k0 = 0; k0 < F_; k0 += 64) {
        __syncthreads();
        #pragma unroll
        for (int r = 0; r < 4; ++r) {
            int sb  = r * 4 + w;                    // sub-block 0..15
            int row = (sb >> 1) * 16 + rowl;        // tile row 0..127
            int kk  = (sb & 1) * 32 + kch * 8;      // k offset 0..63
            __builtin_amdgcn_global_load_lds(
                (const AS1 unsigned int*)(A16 + (size_t)(n0 + row) * F_ + k0 + kk),
                (AS3 unsigned int*)&As[sb * 512], 16, 0, 0);
            __builtin_amdgcn_global_load_lds(
                (const AS1 unsigned int*)(B16 + (size_t)(m0 + row) * F_ + k0 + kk),
                (AS3 unsigned int*)&Bs[sb * 512], 16, 0, 0);
        }
        __syncthreads();
        #pragma unroll
        for (int s = 0; s < 2; ++s) {
            bf16x8 af[4], bfr[4];
            #pragma unroll
            for (int ni = 0; ni < 4; ++ni)
                af[ni] = *(const bf16x8*)&As[((((w & 1) * 4 + ni) * 2 + s) * 512) + lane * 8];
            #pragma unroll
            for (int mi = 0; mi < 4; ++mi)
                bfr[mi] = *(const bf16x8*)&Bs[((((w >> 1) * 4 + mi) * 2 + s) * 512) + lane * 8];
            #pragma unroll
            for (int ni = 0; ni < 4; ++ni)
                #pragma unroll
                for (int mi = 0; mi < 4; ++mi)
                    acc[ni][mi] = __builtin_amdgcn_mfma_f32_16x16x32_bf16(af[ni], bfr[mi], acc[ni][mi], 0, 0, 0);
        }
    }

    // epilogue: E = exp(2*cos); row sums -> total; own-class scatter -> classbuf
    int cls   = m0 >> 9;                 // tile lies in one class (512 % 128 == 0)
    int mbase = (m0 & 511) + mq;
    int colL  = lane & 15;               // C/D: col = lane&15
    int rgrp  = (lane >> 4) * 4;         // C/D: row = (lane>>4)*4 + reg
    #pragma unroll
    for (int ni = 0; ni < 4; ++ni) {
        float Ev[4][4];
        float rsum[4] = {0.f, 0.f, 0.f, 0.f};
        #pragma unroll
        for (int mi = 0; mi < 4; ++mi)
            #pragma unroll
            for (int r = 0; r < 4; ++r) {
                float e = __expf(2.0f * acc[ni][mi][r]);
                Ev[mi][r] = e;
                rsum[r] += e;
            }
        #pragma unroll
        for (int r = 0; r < 4; ++r) {
            float s = rsum[r];
            s += __shfl_xor(s, 1, 64);
            s += __shfl_xor(s, 2, 64);
            s += __shfl_xor(s, 4, 64);
            s += __shfl_xor(s, 8, 64);
            int nrow = nq + ni * 16 + rgrp + r;
            if (colL == 0) atomicAdd(&total[n0 + nrow], s);
            if (lab_s[nrow] == cls) {
                size_t base = (size_t)(n0 + nrow) * 512 + mbase;
                #pragma unroll
                for (int mi = 0; mi < 4; ++mi)
                    classbuf[base + mi * 16 + colL] = Ev[mi][r];
            }
        }
    }
}

// ---------------- kernel 3: per-pixel log terms (wave per pixel) ----------------
__global__ __launch_bounds__(256) void k_terms(const float* __restrict__ classbuf,
                                               const float* __restrict__ total,
                                               const int*   __restrict__ labels,
                                               const int*   __restrict__ mask,
                                               const int*   __restrict__ wmem,
                                               float* __restrict__ class_sum,
                                               int*   __restrict__ class_cnt) {
    int wid  = threadIdx.x >> 6;
    int lane = threadIdx.x & 63;
    int n = blockIdx.x * 4 + wid;
    if (!mask[n]) return;                       // wave-uniform branch
    int lab = labels[n];
    int wm  = wmem[n];
    const float4* p = (const float4*)&classbuf[(size_t)n * 512];
    float4 v0 = p[lane * 2];
    float4 v1 = p[lane * 2 + 1];
    float s = v0.x + v0.y + v0.z + v0.w + v1.x + v1.y + v1.z + v1.w;
    #pragma unroll
    for (int off = 1; off < 64; off <<= 1) s += __shfl_xor(s, off, 64);
    float down = total[n] - s;
    int lo = (wm == 1) ? 0 : 32;                // wm==1 -> first half [0,S)
    float ts = 0.f;
    if (lane >= lo && lane < lo + 32) {
        float vv[8] = {v0.x, v0.y, v0.z, v0.w, v1.x, v1.y, v1.z, v1.w};
        #pragma unroll
        for (int q = 0; q < 8; ++q) {
            float pv = vv[q];
            ts += -logf(pv / (pv + down + 1e-12f) + 1e-12f);
        }
    }
    #pragma unroll
    for (int off = 1; off < 64; off <<= 1) ts += __shfl_xor(ts, off, 64);
    if (lane == 0) {
        atomicAdd(&class_sum[lab], ts);
        atomicAdd(&class_cnt[lab], 1);
    }
}

// ---------------- kernel 4: final class average ----------------
__global__ void k_final(const float* __restrict__ class_sum,
                        const int*   __restrict__ class_cnt,
                        float* __restrict__ out) {
    if (threadIdx.x == 0 && blockIdx.x == 0) {
        float loss = 0.f, kc = 0.f;
        for (int c = 0; c < C_; ++c) {
            int cnt = class_cnt[c];
            if (cnt > 0) {
                loss += class_sum[c] / ((float)cnt * (float)S_);
                kc += 1.f;
            }
        }
        out[0] = loss / fmaxf(kc, 1.f);
    }
}

extern "C" void kernel_launch(void* const* d_in, const int* in_sizes, int n_in,
                              void* d_out, int out_size, void* d_ws, size_t ws_size,
                              hipStream_t stream) {
    const float* mem    = (const float*)d_in[0];
    const float* pred   = (const float*)d_in[1];
    const int*   labels = (const int*)  d_in[2];
    const int*   mask   = (const int*)  d_in[3];
    const int*   wmem   = (const int*)  d_in[4];
    float* out = (float*)d_out;

    float* ws        = (float*)d_ws;
    float* total     = ws;                        // N_ floats (zeroed by k_prep)
    float* class_sum = ws + N_;                   // C_ floats
    int*   class_cnt = (int*)(ws + N_ + C_);      // C_ ints
    float* classbuf  = ws + 16432;                // N_*512 floats = 33.5 MB (16B aligned)
    __hip_bfloat16* A16 = (__hip_bfloat16*)(ws + 16432 + (size_t)N_ * 512);            // 8 MB
    __hip_bfloat16* B16 = (__hip_bfloat16*)(ws + 16432 + (size_t)N_ * 512 + 2097152);  // 4.75 MB

    // prep: 256 convA blocks + M_/4 convB blocks + 17 zero blocks
    k_prep<<<256 + M_ / 4 + 17, 256, 0, stream>>>(pred, mem, A16, B16, ws);

    dim3 g2(M_ / 128, N_ / 128);
    k_mfma<<<g2, 256, 0, stream>>>(A16, B16, labels, total, classbuf);

    k_terms<<<N_ / 4, 256, 0, stream>>>(classbuf, total, labels, mask, wmem,
                                        class_sum, class_cnt);
    k_final<<<1, 64, 0, stream>>>(class_sum, class_cnt, out);
}